// Round 15
// baseline (76.982 us; speedup 1.0000x reference)
//
#include <hip/hip_runtime.h>
#include <hip/hip_fp16.h>
#include <math.h>

// MPS-RNN 2D forward: L=8, M=8, DCUT=6, HL=2, N=64, B=32768
// Round-15 = round-14 + software pipelining: next step's hv-load + T/mv dot2s
// (hv-dependent only, NOT hh-dependent) are computed between this step's acc
// and its reduction tail, filling the DPP/rsqrt latency shadow. Ping-pong
// A/B register sets. Also: carried hhp packs, pre-select-then-broadcast,
// base seeded into md's dot chain.

#define NQ  64
#define BT  256
#define SPB 64

typedef _Float16 h2v __attribute__((ext_vector_type(2)));
typedef __fp16  p2v __attribute__((ext_vector_type(2)));
union H2U { unsigned u; h2v h; __half2 hh; };

static __device__ __forceinline__ h2v pack2(float a, float b) {
    p2v p = __builtin_amdgcn_cvt_pkrtz(a, b);
    h2v r; __builtin_memcpy(&r, &p, sizeof(r));
    return r;
}

#define DPPF(x, ctrl) __int_as_float(__builtin_amdgcn_update_dpp(            \
    __float_as_int(x), __float_as_int(x), (ctrl), 0xF, 0xF, false))
#define QP_XOR1 0xB1   // quad_perm [1,0,3,2]
#define QP_XOR2 0x4E   // quad_perm [2,3,0,1]
#define QP_BC0  0x00
#define QP_BC1  0x55

#if defined(__has_builtin)
#  if __has_builtin(__builtin_amdgcn_rcpf)
#    define FAST_RCP(x) __builtin_amdgcn_rcpf(x)
#  else
#    define FAST_RCP(x) (1.0f / (x))
#  endif
#  if __has_builtin(__builtin_amdgcn_rsqf)
#    define FAST_RSQ(x) __builtin_amdgcn_rsqf(x)
#  else
#    define FAST_RSQ(x) rsqrtf(x)
#  endif
#  if __has_builtin(__builtin_amdgcn_fdot2)
#    define HAS_FDOT2 1
#  endif
#else
#  define FAST_RCP(x) (1.0f / (x))
#  define FAST_RSQ(x) rsqrtf(x)
#endif

static __device__ __forceinline__ float fdot2u(unsigned a, h2v b, float c) {
#ifdef HAS_FDOT2
    H2U u; u.u = a;
    return __builtin_amdgcn_fdot2(u.h, b, c, false);
#else
    H2U u; u.u = a;
    return fmaf((float)u.h.x, (float)b.x, fmaf((float)u.h.y, (float)b.y, c));
#endif
}

// ---- prefetch next column's state + all hv-only dot products ----
#define PREF_M(JN, HVN, HVHN, SCN, NDN, MHN)                                  \
{                                                                             \
    const int slotn_ = ih * 8 + (JN);                                         \
    const float* vrow_ = vsm + (JN) * 768 + s * 12;                           \
    float4 h03_ = *reinterpret_cast<const float4*>(vrow_);                    \
    float2 h45_ = *reinterpret_cast<const float2*>(vrow_ + 4);                \
    HVN[0]=h03_.x; HVN[1]=h03_.y; HVN[2]=h03_.z; HVN[3]=h03_.w;               \
    HVN[4]=h45_.x; HVN[5]=h45_.y;                                             \
    HVHN[0] = pack2(HVN[0], HVN[1]);                                          \
    HVHN[1] = pack2(HVN[2], HVN[3]);                                          \
    HVHN[2] = pack2(HVN[4], HVN[5]);                                          \
    const unsigned* Tbn_ = Tl + (slotn_ * 12 + sub * 3) * 24;                 \
    _Pragma("unroll")                                                         \
    for (int lr = 0; lr < 3; ++lr) {                                          \
        const unsigned* Tr_ = Tbn_ + lr * 24;                                 \
        uint4 tA_ = *reinterpret_cast<const uint4*>(Tr_);                     \
        uint4 tB_ = *reinterpret_cast<const uint4*>(Tr_ + 4);                 \
        uint4 tC_ = *reinterpret_cast<const uint4*>(Tr_ + 8);                 \
        uint4 tD_ = *reinterpret_cast<const uint4*>(Tr_ + 12);                \
        uint4 tE_ = *reinterpret_cast<const uint4*>(Tr_ + 16);                \
        uint4 tF_ = *reinterpret_cast<const uint4*>(Tr_ + 20);                \
        SCN[lr*6+0] = fdot2u(tA_.x, HVHN[0], fdot2u(tA_.y, HVHN[1], fdot2u(tA_.z, HVHN[2], 0.f))); \
        SCN[lr*6+1] = fdot2u(tA_.w, HVHN[0], fdot2u(tB_.x, HVHN[1], fdot2u(tB_.y, HVHN[2], 0.f))); \
        SCN[lr*6+2] = fdot2u(tB_.z, HVHN[0], fdot2u(tB_.w, HVHN[1], fdot2u(tC_.x, HVHN[2], 0.f))); \
        SCN[lr*6+3] = fdot2u(tC_.y, HVHN[0], fdot2u(tC_.z, HVHN[1], fdot2u(tC_.w, HVHN[2], 0.f))); \
        SCN[lr*6+4] = fdot2u(tD_.x, HVHN[0], fdot2u(tD_.y, HVHN[1], fdot2u(tD_.z, HVHN[2], 0.f))); \
        SCN[lr*6+5] = fdot2u(tD_.w, HVHN[0], fdot2u(tE_.x, HVHN[1], fdot2u(tE_.y, HVHN[2], 0.f))); \
        NDN[lr] = fdot2u(tF_.y, HVHN[0], fdot2u(tF_.z, HVHN[1], fdot2u(tF_.w, HVHN[2], 0.f)));     \
        MHN[lr*3+0] = tE_.z; MHN[lr*3+1] = tE_.w; MHN[lr*3+2] = tF_.x;        \
    }                                                                         \
}

// ---- one recurrence step (consumes CUR set; optionally prefetches NXT) ----
#define STEP_M(QQ, HV, HVH, SC, ND, MH, DOPREF, HVN, HVHN, SCN, NDN, MHN)     \
{                                                                             \
    const int qq_ = (QQ);                                                     \
    const int j_  = ih ? 7 - qq_ : qq_;                                       \
    const int slot_ = ih * 8 + j_;                                            \
    const int siteg_ = ch * 16 + slot_;                                       \
    const float* VEb_ = VE + (slot_ * 4 + sub) * 8;                           \
    float4 ve0_ = *reinterpret_cast<const float4*>(VEb_);                     \
    float2 ve1_ = *reinterpret_cast<const float2*>(VEb_ + 4);                 \
    const float vv_[3] = { ve0_.x, ve0_.y, ve0_.z };                          \
    const float e2_[3] = { ve0_.w, ve1_.x, ve1_.y };                          \
    const float* wq_ = Wp + siteg_ * 6;                                       \
    const float  ck_ = Cp[siteg_];                                            \
    float acc_[3];                                                            \
    _Pragma("unroll")                                                         \
    for (int lr = 0; lr < 3; ++lr) {                                          \
        const float hho_ = ohi ? hh[lr + 3] : hh[lr];                         \
        const float hvo_ = ohi ? HV[lr + 3] : HV[lr];                         \
        const float seed_ = vv_[lr] + hho_ + hvo_;                            \
        float md_ = fdot2u(MH[lr*3+0], hhp0, fdot2u(MH[lr*3+1], hhp1,         \
                    fdot2u(MH[lr*3+2], hhp2, seed_)));                        \
        float ta_ = fmaf(SC[lr*6+0], hh[0], fmaf(SC[lr*6+2], hh[2], SC[lr*6+4] * hh[4])); \
        float tb_ = fmaf(SC[lr*6+1], hh[1], fmaf(SC[lr*6+3], hh[3], SC[lr*6+5] * hh[5])); \
        acc_[lr] = (ta_ + tb_) + (md_ + ND[lr]);                              \
    }                                                                         \
    if (DOPREF) {                                                             \
        const int jn_ = ih ? 7 - (qq_ + 1) : (qq_ + 1);                       \
        PREF_M(jn_, HVN, HVHN, SCN, NDN, MHN)                                 \
    }                                                                         \
    float q0_ = acc_[0]*acc_[0], q1_ = acc_[1]*acc_[1], q2_ = acc_[2]*acc_[2];\
    float ssl_ = (q0_ + q1_) + q2_;                                           \
    float pq_  = fmaf(e2_[0], q0_, fmaf(e2_[1], q1_, e2_[2] * q2_));          \
    float s1_ = ssl_ + DPPF(ssl_, QP_XOR1);                                   \
    float ssq_ = s1_ + DPPF(s1_, QP_XOR2);                                    \
    float p1_ = pq_ + DPPF(pq_, QP_XOR1);                                     \
    float px_ = DPPF(p1_, QP_XOR2);                                           \
    const float inv_ = FAST_RSQ(ssq_ + 1e-12f);                               \
    const int sel_ = (cbr >> qq_) & 1;                                        \
    const float qsel_ = (mya == sel_) ? p1_ : px_;                            \
    amp2 *= qsel_ * FAST_RCP(p1_ + px_);                                      \
    float an0_ = acc_[0] * inv_, an1_ = acc_[1] * inv_, an2_ = acc_[2] * inv_;\
    float sw0_ = DPPF(an0_, QP_XOR2);                                         \
    float sw1_ = DPPF(an1_, QP_XOR2);                                         \
    float sw2_ = DPPF(an2_, QP_XOR2);                                         \
    an0_ = sel_ ? sw0_ : an0_;                                                \
    an1_ = sel_ ? sw1_ : an1_;                                                \
    an2_ = sel_ ? sw2_ : an2_;                                                \
    hh[0] = DPPF(an0_, QP_BC0); hh[3] = DPPF(an0_, QP_BC1);                   \
    hh[1] = DPPF(an1_, QP_BC0); hh[4] = DPPF(an1_, QP_BC1);                   \
    hh[2] = DPPF(an2_, QP_BC0); hh[5] = DPPF(an2_, QP_BC1);                   \
    hhp0 = pack2(hh[0], hh[1]); hhp1 = pack2(hh[2], hh[3]); hhp2 = pack2(hh[4], hh[5]); \
    float pA_ = fmaf(wq_[1], hh[1], wq_[0] * hh[0]);                          \
    float pB_ = fmaf(wq_[3], hh[3], wq_[2] * hh[2]);                          \
    float pC_ = fmaf(wq_[5], hh[5], fmaf(wq_[4], hh[4], ck_));                \
    phi += (pA_ + pB_) + pC_;                                                 \
    if (sub == 0) {                                                           \
        float* vw_ = vsm + j_ * 768 + s * 12;                                 \
        *reinterpret_cast<float4*>(vw_) = make_float4(hh[0], hh[1], hh[2], hh[3]); \
        *reinterpret_cast<float2*>(vw_ + 4) = make_float2(hh[4], hh[5]);      \
    }                                                                         \
}

__global__ __launch_bounds__(BT, 2) void mps_rnn15(
    const float* __restrict__ Mh,   // (L,M,2,6,6)
    const float* __restrict__ Mv,   // (L,M,2,6,6)
    const float* __restrict__ Vp,   // (L,M,2,6)
    const float* __restrict__ Tp,   // (L,M,2,6,6,6)
    const float* __restrict__ Wp,   // (L,M,6)
    const float* __restrict__ Cp,   // (L,M)
    const float* __restrict__ Ep,   // (L,M,6)
    const int*   __restrict__ X,    // (B,64)
    float*       __restrict__ out,
    int Bn, int writeImag)
{
    // merged fp16 rows: [site][row(=a*6+o)][24 uints]: 18 T | 3 mh | 3 mv
    __shared__ unsigned Tl[16 * 12 * 24];    // 18432 B
    __shared__ float    VE [16 * 4 * 8];     // 2048 B (v0 v1 v2 e0^2 e1^2 e2^2 . .)
    __shared__ float    vsm[8 * 64 * 12];    // 24576 B vertical state [j][s][12]

    const int t   = threadIdx.x;
    const int sub = t & 3;
    const int s   = t >> 2;
    int b = blockIdx.x * SPB + s;
    const bool valid = (b < Bn);
    if (!valid) b = Bn - 1;          // clamp loads; no early return (barriers!)

    // cooperative bit pack (each lane 16 qubits, OR-combine across group)
    unsigned long long bits;
    {
        const int4* xr = reinterpret_cast<const int4*>(X + (size_t)b * NQ + sub * 16);
        unsigned long long part = 0ull;
        #pragma unroll
        for (int q = 0; q < 4; ++q) {
            int4 v = xr[q];
            part |= (unsigned long long)(v.x & 1) << (4 * q + 0);
            part |= (unsigned long long)(v.y & 1) << (4 * q + 1);
            part |= (unsigned long long)(v.z & 1) << (4 * q + 2);
            part |= (unsigned long long)(v.w & 1) << (4 * q + 3);
        }
        bits = part << (16 * sub);
        bits |= __shfl_xor(bits, 1, 64);
        bits |= __shfl_xor(bits, 2, 64);
    }

    for (int u = t; u < 8 * 64 * 12; u += BT) vsm[u] = 0.f;

    const int mya = sub >> 1;
    const int ohi = sub & 1;

    float hh[6];
    h2v hhp0, hhp1, hhp2;
    float amp2 = 1.f, phi = 0.f;

    for (int ch = 0; ch < 4; ++ch) {
        __syncthreads();             // previous chunk fully consumed
        // ---- stage chunk ch (sites 16ch..16ch+15) — identical to r14
        {
            const float2* gT = reinterpret_cast<const float2*>(Tp + ch * 6912);
            for (int p = t; p < 3456; p += BT) {
                int site = p / 216, rr = p - site * 216;
                int row = rr / 18,  w  = rr - row * 18;
                float2 v = gT[p];
                H2U hu; hu.hh = __floats2half2_rn(v.x, v.y);
                Tl[(site * 12 + row) * 24 + w] = hu.u;
            }
            const float2* gH = reinterpret_cast<const float2*>(Mh + ch * 1152);
            const float2* gV = reinterpret_cast<const float2*>(Mv + ch * 1152);
            for (int p = t; p < 576; p += BT) {
                int site = p / 36, rr = p - site * 36;
                int row = rr / 3,  w  = rr - row * 3;
                float2 vh = gH[p], vv2 = gV[p];
                H2U a; a.hh = __floats2half2_rn(vh.x, vh.y);
                H2U c; c.hh = __floats2half2_rn(vv2.x, vv2.y);
                Tl[(site * 12 + row) * 24 + 18 + w] = a.u;
                Tl[(site * 12 + row) * 24 + 21 + w] = c.u;
            }
            if (t < 192) {
                int site = t / 12, q = t - site * 12;
                int sb = q / 3,    c = q - sb * 3;
                VE[(site * 4 + sb) * 8 + c] = Vp[ch * 192 + t];
                float e = Ep[ch * 96 + site * 6 + (sb & 1) * 3 + c];
                VE[(site * 4 + sb) * 8 + 3 + c] = e * e;
            }
        }
        __syncthreads();             // chunk visible

        #pragma unroll
        for (int ih = 0; ih < 2; ++ih) {
            const unsigned cbr = (unsigned)(bits >> (ch * 16 + ih * 8)) & 0xFFu;

            // ping-pong register sets
            float hvA[6], hvB[6];
            h2v hvhA[3], hvhB[3];
            float scA[18], scB[18], ndA[3], ndB[3];
            unsigned mhA[9], mhB[9];

            // row prologue: state + hv-only dots for the first column
            {
                const int j0 = ih ? 7 : 0;
                PREF_M(j0, hvA, hvhA, scA, ndA, mhA)
            }
            #pragma unroll
            for (int o = 0; o < 6; ++o) hh[o] = 1.f;   // left boundary
            { H2U one; one.u = 0x3C003C00u; hhp0 = one.h; hhp1 = one.h; hhp2 = one.h; }

            #pragma unroll 1
            for (int qp = 0; qp < 4; ++qp) {
                STEP_M(2 * qp,     hvA, hvhA, scA, ndA, mhA, 1,
                                   hvB, hvhB, scB, ndB, mhB)
                STEP_M(2 * qp + 1, hvB, hvhB, scB, ndB, mhB, (qp < 3),
                                   hvA, hvhA, scA, ndA, mhA)
            }
        }
    }

    if (sub == 0 && valid) {
        const float amp = sqrtf(amp2);
        if (writeImag) {
            out[2 * b + 0] = amp * cosf(phi);
            out[2 * b + 1] = amp * sinf(phi);
        } else {
            out[b] = amp * cosf(phi);
        }
    }
}

extern "C" void kernel_launch(void* const* d_in, const int* in_sizes, int n_in,
                              void* d_out, int out_size, void* d_ws, size_t ws_size,
                              hipStream_t stream) {
    const float* Mh = (const float*)d_in[0];
    const float* Mv = (const float*)d_in[1];
    const float* Vp = (const float*)d_in[2];
    const float* Tp = (const float*)d_in[3];
    const float* Wp = (const float*)d_in[4];
    const float* Cp = (const float*)d_in[5];
    const float* Ep = (const float*)d_in[6];
    const int*   X  = (const int*)d_in[7];
    float* out = (float*)d_out;

    const int Bn = in_sizes[7] / NQ;                 // 32768
    const int writeImag = (out_size >= 2 * Bn) ? 1 : 0;
    const int grid = (Bn + SPB - 1) / SPB;           // 512 blocks of 256 threads

    mps_rnn15<<<grid, BT, 0, stream>>>(Mh, Mv, Vp, Tp, Wp, Cp, Ep, X, out,
                                       Bn, writeImag);
}

// Round 16
// 65.035 us; speedup vs baseline: 1.1837x; 1.1837x over previous
//
#include <hip/hip_runtime.h>
#include <hip/hip_fp16.h>
#include <math.h>

// MPS-RNN 2D forward: L=8, M=8, DCUT=6, HL=2, N=64, B=32768
// Round-16 = round-14 base (r15 pipelining reverted) + three cuts:
//  (1) residual terms folded into staged Mh/Mv fp16 diagonals (+1.0),
//      md seeded with V -> no per-step cndmask/adds for hho/hvo
//  (2) vertical state stored as RTZ-packed fp16 (bit-identical math),
//      1 b128 read + 1 b128 write, no repacking
//  (3) W+C staged packed per site -> phase = 3 dot2 on the hhp packs

#define NQ  64
#define BT  256
#define SPB 64

typedef _Float16 h2v __attribute__((ext_vector_type(2)));
typedef __fp16  p2v __attribute__((ext_vector_type(2)));
union H2U { unsigned u; h2v h; __half2 hh; };

static __device__ __forceinline__ h2v pack2(float a, float b) {
    p2v p = __builtin_amdgcn_cvt_pkrtz(a, b);
    h2v r; __builtin_memcpy(&r, &p, sizeof(r));
    return r;
}
static __device__ __forceinline__ h2v u2h(unsigned u) {
    h2v r; __builtin_memcpy(&r, &u, sizeof(r));
    return r;
}
static __device__ __forceinline__ unsigned h2u(h2v h) {
    unsigned r; __builtin_memcpy(&r, &h, sizeof(r));
    return r;
}

#define DPPF(x, ctrl) __int_as_float(__builtin_amdgcn_update_dpp(            \
    __float_as_int(x), __float_as_int(x), (ctrl), 0xF, 0xF, false))
#define QP_XOR1 0xB1   // quad_perm [1,0,3,2]
#define QP_XOR2 0x4E   // quad_perm [2,3,0,1]
#define QP_BC0  0x00
#define QP_BC1  0x55

#if defined(__has_builtin)
#  if __has_builtin(__builtin_amdgcn_rcpf)
#    define FAST_RCP(x) __builtin_amdgcn_rcpf(x)
#  else
#    define FAST_RCP(x) (1.0f / (x))
#  endif
#  if __has_builtin(__builtin_amdgcn_rsqf)
#    define FAST_RSQ(x) __builtin_amdgcn_rsqf(x)
#  else
#    define FAST_RSQ(x) rsqrtf(x)
#  endif
#  if __has_builtin(__builtin_amdgcn_fdot2)
#    define HAS_FDOT2 1
#  endif
#else
#  define FAST_RCP(x) (1.0f / (x))
#  define FAST_RSQ(x) rsqrtf(x)
#endif

static __device__ __forceinline__ float fdot2u(unsigned a, h2v b, float c) {
#ifdef HAS_FDOT2
    H2U u; u.u = a;
    return __builtin_amdgcn_fdot2(u.h, b, c, false);
#else
    H2U u; u.u = a;
    return fmaf((float)u.h.x, (float)b.x, fmaf((float)u.h.y, (float)b.y, c));
#endif
}

__global__ __launch_bounds__(BT, 1) void mps_rnn16(
    const float* __restrict__ Mh,   // (L,M,2,6,6)
    const float* __restrict__ Mv,   // (L,M,2,6,6)
    const float* __restrict__ Vp,   // (L,M,2,6)
    const float* __restrict__ Tp,   // (L,M,2,6,6,6)
    const float* __restrict__ Wp,   // (L,M,6)
    const float* __restrict__ Cp,   // (L,M)
    const float* __restrict__ Ep,   // (L,M,6)
    const int*   __restrict__ X,    // (B,64)
    float*       __restrict__ out,
    int Bn, int writeImag)
{
    // merged fp16 rows: [site][row(=a*6+o)][24 uints]: 18 T | 3 mh(+diag) | 3 mv(+diag)
    __shared__ unsigned Tl[16 * 12 * 24];    // 18432 B
    __shared__ float    VE [16 * 4 * 8];     // 2048 B (v0 v1 v2 e0^2 e1^2 e2^2 . .)
    __shared__ uint4    Wl [16];             // 256 B  (w01 w23 w45 | ck as f32 bits)
    __shared__ unsigned vsm[8 * 64 * 4];     // 8192 B vertical state [j][s][4] packed fp16

    const int t   = threadIdx.x;
    const int sub = t & 3;
    const int s   = t >> 2;
    int b = blockIdx.x * SPB + s;
    const bool valid = (b < Bn);
    if (!valid) b = Bn - 1;          // clamp loads; no early return (barriers!)

    // cooperative bit pack (each lane 16 qubits, OR-combine across group)
    unsigned long long bits;
    {
        const int4* xr = reinterpret_cast<const int4*>(X + (size_t)b * NQ + sub * 16);
        unsigned long long part = 0ull;
        #pragma unroll
        for (int q = 0; q < 4; ++q) {
            int4 v = xr[q];
            part |= (unsigned long long)(v.x & 1) << (4 * q + 0);
            part |= (unsigned long long)(v.y & 1) << (4 * q + 1);
            part |= (unsigned long long)(v.z & 1) << (4 * q + 2);
            part |= (unsigned long long)(v.w & 1) << (4 * q + 3);
        }
        bits = part << (16 * sub);
        bits |= __shfl_xor(bits, 1, 64);
        bits |= __shfl_xor(bits, 2, 64);
    }

    for (int u = t; u < 8 * 64 * 4; u += BT) vsm[u] = 0u;

    const int mya = sub >> 1;
    const int ohi = sub & 1;
    (void)ohi;

    float hh[6];
    h2v hhp0, hhp1, hhp2;
    float amp2 = 1.f, phi = 0.f;

    for (int ch = 0; ch < 4; ++ch) {
        __syncthreads();             // previous chunk fully consumed
        // ---- stage chunk ch (sites 16ch..16ch+15)
        {
            // T: 216 fp32-pairs/site -> h2, row = pair/18, w = pair%18
            const float2* gT = reinterpret_cast<const float2*>(Tp + ch * 6912);
            for (int p = t; p < 3456; p += BT) {
                int site = p / 216, rr = p - site * 216;
                int row = rr / 18,  w  = rr - row * 18;
                float2 v = gT[p];
                H2U hu; hu.hh = __floats2half2_rn(v.x, v.y);
                Tl[(site * 12 + row) * 24 + w] = hu.u;
            }
            // Mh/Mv: 36 pairs/site each, row = rr/3, w = rr%3.
            // Residual fold: +1.0 on the diagonal element (c == o_r) pre-conversion.
            const float2* gH = reinterpret_cast<const float2*>(Mh + ch * 1152);
            const float2* gV = reinterpret_cast<const float2*>(Mv + ch * 1152);
            for (int p = t; p < 576; p += BT) {
                int site = p / 36, rr = p - site * 36;
                int row = rr / 3,  w  = rr - row * 3;
                int o_r = row - ((row >= 6) ? 6 : 0);     // row % 6
                float2 vh = gH[p], vv2 = gV[p];
                if ((o_r >> 1) == w) {
                    if (o_r & 1) { vh.y += 1.f; vv2.y += 1.f; }
                    else         { vh.x += 1.f; vv2.x += 1.f; }
                }
                H2U a; a.hh = __floats2half2_rn(vh.x, vh.y);
                H2U c; c.hh = __floats2half2_rn(vv2.x, vv2.y);
                Tl[(site * 12 + row) * 24 + 18 + w] = a.u;
                Tl[(site * 12 + row) * 24 + 21 + w] = c.u;
            }
            // V + eta^2 packed (fp32)
            if (t < 192) {
                int site = t / 12, q = t - site * 12;
                int sb = q / 3,    c = q - sb * 3;
                VE[(site * 4 + sb) * 8 + c] = Vp[ch * 192 + t];
                float e = Ep[ch * 96 + site * 6 + (sb & 1) * 3 + c];
                VE[(site * 4 + sb) * 8 + 3 + c] = e * e;
            } else if (t < 208) {
                // W packed fp16 pairs + C as f32 bits
                int site = t - 192;
                const float2* gw = reinterpret_cast<const float2*>(Wp) + ch * 48 + site * 3;
                float2 w01 = gw[0], w23 = gw[1], w45 = gw[2];
                H2U u0, u1, u2;
                u0.hh = __floats2half2_rn(w01.x, w01.y);
                u1.hh = __floats2half2_rn(w23.x, w23.y);
                u2.hh = __floats2half2_rn(w45.x, w45.y);
                Wl[site] = make_uint4(u0.u, u1.u, u2.u,
                                      __float_as_uint(Cp[ch * 16 + site]));
            }
        }
        __syncthreads();             // chunk visible

        #pragma unroll
        for (int ih = 0; ih < 2; ++ih) {
            const unsigned cbr = (unsigned)(bits >> (ch * 16 + ih * 8)) & 0xFFu;

            #pragma unroll 2
            for (int qq = 0; qq < 8; ++qq) {
                const int j    = ih ? 7 - qq : qq;      // snake column
                const int slot = ih * 8 + j;

                const unsigned* Tb = Tl + (slot * 12 + sub * 3) * 24;
                const float*   VEb = VE + (slot * 4 + sub) * 8;

                if (qq == 0) {                          // left boundary
                    #pragma unroll
                    for (int o = 0; o < 6; ++o) hh[o] = 1.f;
                    H2U one; one.u = 0x3C003C00u;
                    hhp0 = one.h; hhp1 = one.h; hhp2 = one.h;
                }

                // vertical state: packed fp16, one b128 read
                uint4 hvu = *reinterpret_cast<const uint4*>(vsm + j * 256 + s * 4);
                const h2v hvh0 = u2h(hvu.x);
                const h2v hvh1 = u2h(hvu.y);
                const h2v hvh2 = u2h(hvu.z);

                float4 ve0 = *reinterpret_cast<const float4*>(VEb);     // v0 v1 v2 e0
                float2 ve1 = *reinterpret_cast<const float2*>(VEb + 4); // e1 e2
                const float vv_[3] = { ve0.x, ve0.y, ve0.z };
                const float e2_[3] = { ve0.w, ve1.x, ve1.y };

                float acc[3];
                #pragma unroll
                for (int lr = 0; lr < 3; ++lr) {
                    const unsigned* Tr = Tb + lr * 24;
                    uint4 tA = *reinterpret_cast<const uint4*>(Tr);      // T 0..3
                    uint4 tB = *reinterpret_cast<const uint4*>(Tr + 4);  // T 4..7
                    uint4 tC = *reinterpret_cast<const uint4*>(Tr + 8);  // T 8..11
                    uint4 tD = *reinterpret_cast<const uint4*>(Tr + 12); // T 12..15
                    uint4 tE = *reinterpret_cast<const uint4*>(Tr + 16); // T16 T17 mh0 mh1
                    uint4 tF = *reinterpret_cast<const uint4*>(Tr + 20); // mh2 mv0 mv1 mv2
                    const unsigned tw[18] = {tA.x,tA.y,tA.z,tA.w, tB.x,tB.y,tB.z,tB.w,
                                             tC.x,tC.y,tC.z,tC.w, tD.x,tD.y,tD.z,tD.w,
                                             tE.x,tE.y};
                    float sc[6];
                    #pragma unroll
                    for (int c = 0; c < 6; ++c)
                        sc[c] = fdot2u(tw[c*3+0], hvh0,
                                fdot2u(tw[c*3+1], hvh1,
                                fdot2u(tw[c*3+2], hvh2, 0.f)));

                    float ta = fmaf(sc[0], hh[0], fmaf(sc[2], hh[2], sc[4]*hh[4]));
                    float tb = fmaf(sc[1], hh[1], fmaf(sc[3], hh[3], sc[5]*hh[5]));
                    float md = fdot2u(tE.z, hhp0, fdot2u(tE.w, hhp1,
                               fdot2u(tF.x, hhp2, vv_[lr])));   // diag-folded + V seed
                    float nd = fdot2u(tF.y, hvh0, fdot2u(tF.z, hvh1,
                               fdot2u(tF.w, hvh2, 0.f)));       // diag-folded
                    acc[lr] = (ta + tb) + (md + nd);
                }

                // 4-lane reductions via DPP quad_perm (pure VALU, no LDS)
                float q0_ = acc[0]*acc[0], q1_ = acc[1]*acc[1], q2_ = acc[2]*acc[2];
                float ssl = (q0_ + q1_) + q2_;
                float pq  = fmaf(e2_[0], q0_, fmaf(e2_[1], q1_, e2_[2] * q2_));
                float s1  = ssl + DPPF(ssl, QP_XOR1);
                float ssq = s1 + DPPF(s1, QP_XOR2);
                float p1  = pq + DPPF(pq, QP_XOR1);
                float px  = DPPF(p1, QP_XOR2);
                const float inv = FAST_RSQ(ssq + 1e-12f);

                const int sel = (cbr >> qq) & 1;
                const float qsel = (mya == sel) ? p1 : px;
                amp2 *= qsel * FAST_RCP(p1 + px);

                // normalize, XOR2-swap pre-select, then 6 quad-broadcasts
                float an0 = acc[0] * inv, an1 = acc[1] * inv, an2 = acc[2] * inv;
                float sw0 = DPPF(an0, QP_XOR2);
                float sw1 = DPPF(an1, QP_XOR2);
                float sw2 = DPPF(an2, QP_XOR2);
                an0 = sel ? sw0 : an0;
                an1 = sel ? sw1 : an1;
                an2 = sel ? sw2 : an2;
                hh[0] = DPPF(an0, QP_BC0); hh[3] = DPPF(an0, QP_BC1);
                hh[1] = DPPF(an1, QP_BC0); hh[4] = DPPF(an1, QP_BC1);
                hh[2] = DPPF(an2, QP_BC0); hh[5] = DPPF(an2, QP_BC1);
                hhp0 = pack2(hh[0], hh[1]);
                hhp1 = pack2(hh[2], hh[3]);
                hhp2 = pack2(hh[4], hh[5]);

                // phase via packed W dot2s (+ C seed)
                uint4 wv = Wl[slot];
                phi = fdot2u(wv.x, hhp0, fdot2u(wv.y, hhp1,
                      fdot2u(wv.z, hhp2, __uint_as_float(wv.w) + phi)));

                if (sub == 0) {
                    *reinterpret_cast<uint4*>(vsm + j * 256 + s * 4) =
                        make_uint4(h2u(hhp0), h2u(hhp1), h2u(hhp2), 0u);
                }
            }
        }
    }

    if (sub == 0 && valid) {
        const float amp = sqrtf(amp2);
        if (writeImag) {
            out[2 * b + 0] = amp * cosf(phi);
            out[2 * b + 1] = amp * sinf(phi);
        } else {
            out[b] = amp * cosf(phi);
        }
    }
}

extern "C" void kernel_launch(void* const* d_in, const int* in_sizes, int n_in,
                              void* d_out, int out_size, void* d_ws, size_t ws_size,
                              hipStream_t stream) {
    const float* Mh = (const float*)d_in[0];
    const float* Mv = (const float*)d_in[1];
    const float* Vp = (const float*)d_in[2];
    const float* Tp = (const float*)d_in[3];
    const float* Wp = (const float*)d_in[4];
    const float* Cp = (const float*)d_in[5];
    const float* Ep = (const float*)d_in[6];
    const int*   X  = (const int*)d_in[7];
    float* out = (float*)d_out;

    const int Bn = in_sizes[7] / NQ;                 // 32768
    const int writeImag = (out_size >= 2 * Bn) ? 1 : 0;
    const int grid = (Bn + SPB - 1) / SPB;           // 512 blocks of 256 threads

    mps_rnn16<<<grid, BT, 0, stream>>>(Mh, Mv, Vp, Tp, Wp, Cp, Ep, X, out,
                                       Bn, writeImag);
}